// Round 1
// 314.387 us; speedup vs baseline: 1.0345x; 1.0345x over previous
//
#include <hip/hip_runtime.h>
#include <cstdint>
#include <cstddef>

// ExpertGather: Y[b,e,k,j] = sum_i X[b, ind[b,e,k], i] * W[e,i,j]
// B=4 T=4096 I=1024 E=16 K=512 J=1024
// Round 4: 8-phase-style deep pipeline (T3+T4+T5 from the technique catalog).
//  - LDS = ring of 4 x 16KB units per operand (unit = 256 rows x 32 halves),
//    128 KB total, 1 block/CU.
//  - Per K-tile (BK=64): 4 phases (ks,mh), each {8 ds_read_b128; stage 1 unit
//    (2 global_load_lds/thread); barrier; lgkmcnt(0)+sched_barrier; setprio(1);
//    16 MFMA; setprio(0); barrier}.
//  - Staging runs 5-6 phases ahead: P1/P2(t) stage tile t+1 k1-units,
//    P3/P4(t) stage tile t+2 k0-units. Every stage target slot's last reader
//    drained at an earlier barrier => race-free by construction.
//  - Counted vmcnt(4) at tile boundary (2 newest units stay in flight);
//    vmcnt(0) only before the last tile.
//  - XOR swizzle: pair-line layout, pos = ((r&1)*4 | c) ^ ((r>>1)&7); inverse
//    swizzle applied on per-lane global source (rule 21: both-sides).
//  - Epilogue + XCD-swizzled block mapping unchanged (verified).
// cvt_x + cvt_w fused into one launch.

typedef float    floatx4 __attribute__((ext_vector_type(4)));
typedef _Float16 half8   __attribute__((ext_vector_type(8)));

constexpr int Bc = 4, Tc = 4096, Ic = 1024, Ec = 16, Kc = 512, Jc = 1024;
constexpr int BM = 256, BN = 256, BK = 64, NT = 512;
constexpr int NKT = Ic / BK;   // 16 K-tiles
constexpr int UNIT = 16384;    // one K-half unit: 256 rows x 32 halves x 2B
constexpr int BOFF = 4 * UNIT; // B-region byte offset in smem

__device__ __forceinline__ void async16(const void* g, void* l) {
  __builtin_amdgcn_global_load_lds(
      (const __attribute__((address_space(1))) uint32_t*)g,
      (__attribute__((address_space(3))) uint32_t*)l, 16, 0, 0);
}

// ---------- fused pre-pass: W transpose->fp16 (blocks 0..4095), X->fp16 (rest) ----------
__global__ void cvt_kernel(const float* __restrict__ X, _Float16* __restrict__ Xh, int n8,
                           const float* __restrict__ W, _Float16* __restrict__ WT) {
  __shared__ float tile[64][65];
  const int bidx = blockIdx.x;
  if (bidx >= Ec * 256) {
    // ---- X fp32 -> fp16, 16B stores ----
    int i = (bidx - Ec * 256) * blockDim.x + threadIdx.x;
    const int stride = 2048 * blockDim.x;
    for (; i < n8; i += stride) {
      floatx4 v0 = ((const floatx4*)X)[2 * i];
      floatx4 v1 = ((const floatx4*)X)[2 * i + 1];
      half8 h;
      h[0] = (_Float16)v0.x; h[1] = (_Float16)v0.y; h[2] = (_Float16)v0.z; h[3] = (_Float16)v0.w;
      h[4] = (_Float16)v1.x; h[5] = (_Float16)v1.y; h[6] = (_Float16)v1.z; h[7] = (_Float16)v1.w;
      ((half8*)Xh)[i] = h;
    }
    return;
  }
  // ---- W [E][I][J] fp32 -> WT [E][J][I] fp16 ----
  const int bid = bidx;
  const int e  = bid >> 8;
  const int i0 = ((bid >> 4) & 15) * 64;
  const int j0 = (bid & 15) * 64;
  const int tid = threadIdx.x;
  const int r  = tid >> 4;
  const int c4 = tid & 15;
  const float* src = W + ((size_t)e << 20) + (size_t)i0 * Jc + j0;
#pragma unroll
  for (int s = 0; s < 4; s++) {
    int rr = r + s * 16;
    floatx4 v = *(const floatx4*)(src + (size_t)rr * Jc + c4 * 4);
    tile[rr][c4 * 4 + 0] = v.x; tile[rr][c4 * 4 + 1] = v.y;
    tile[rr][c4 * 4 + 2] = v.z; tile[rr][c4 * 4 + 3] = v.w;
  }
  __syncthreads();
  const int jj = tid >> 2;
  const int ig = tid & 3;
  half8 hv0, hv1;
#pragma unroll
  for (int q = 0; q < 8; q++) hv0[q] = (_Float16)tile[ig * 16 + q][jj];
#pragma unroll
  for (int q = 0; q < 8; q++) hv1[q] = (_Float16)tile[ig * 16 + 8 + q][jj];
  _Float16* dst = WT + ((size_t)e << 20) + (size_t)(j0 + jj) * Ic + i0 + ig * 16;
  ((half8*)dst)[0] = hv0;
  ((half8*)dst)[1] = hv1;
}

// ---------- main grouped GEMM ----------
// Grid 512 = 8 chunks x 8 sharers x 8 XCD-slots (unchanged, verified).
// MFMA layouts (m89-verified): A/B m(n)=lane&15, k=(lane>>4)*8+j;
// C/D col=lane&15, row=(lane>>4)*4+reg.
__global__ __launch_bounds__(NT, 2) void gemm_kernel(
    const int* __restrict__ ind32,
    const _Float16* __restrict__ Xh, const _Float16* __restrict__ WT,
    float* __restrict__ Y) {
  __shared__ alignas(16) unsigned char smem[8 * UNIT];  // 128 KB ring
  __shared__ int rowid[BM];
  __shared__ int is64_s;
  float* lbuf = (float*)smem;   // epilogue reuse (32x257 floats fits)
  char* smemc = (char*)smem;

  const int tid = threadIdx.x;
  const int bid = blockIdx.x;
  const int x = bid & 7, s = (bid >> 3) & 7, chunk = bid >> 6;
  const int g = chunk * 8 + x;       // 0..63 B-tile group
  const int e = g >> 2, nt = g & 3;  // expert, j-tile
  const int b = s >> 1, mt = s & 1;  // batch, k-tile
  const int be = b * Ec + e;
  const int k0 = mt * BM;
  const int j0 = nt * BN;

  // index dtype probe (int64 vs int32 storage), wave-parallel
  if (tid < 64) {
    int v = ind32[2 * tid + 1];
    unsigned long long m = __ballot(v != 0);
    if (tid == 0) is64_s = (m == 0ULL) ? 1 : 0;
  }
  __syncthreads();
  if (tid < BM) {
    int idx = be * Kc + k0 + tid;
    rowid[tid] = is64_s ? ind32[2 * idx] : ind32[idx];
  }
  __syncthreads();

  const int lane = tid & 63;
  const int wave = tid >> 6;           // 0..7
  const int wmb = (wave >> 2) * 128;   // wave m base (2 rows of waves)
  const int wnb = (wave & 3) * 64;     // wave n base (4 cols of waves)
  const int quad = lane >> 4;
  const int tr = lane & 15;

  // ---- staging source pointers (inverse-swizzled; dest is linear lane order) ----
  // slot s = wave*128 + q*64 + lane; r2=s>>3; p=s&7; pos=p^(r2&7);
  // row = 2*r2 + (pos>>2); chunk c = pos&3 (8 halves each).
  const _Float16* aSrc[2];
  const _Float16* bSrc[2];
#pragma unroll
  for (int q = 0; q < 2; q++) {
    const int sl = wave * 128 + q * 64 + lane;
    const int r2 = sl >> 3, p = sl & 7;
    const int pos = p ^ (r2 & 7);
    const int r = 2 * r2 + (pos >> 2);
    const int c = pos & 3;
    aSrc[q] = Xh + ((size_t)b * Tc + rowid[r]) * Ic + c * 8;
    bSrc[q] = WT + ((size_t)e * Jc + j0 + r) * Ic + c * 8;
  }
  const int wdst = wave * 2048;  // wave-uniform LDS dest base within a unit

  // ---- swizzled ds_read byte offsets within a unit ----
  int offA[2][4], offB[4];
#pragma unroll
  for (int mh = 0; mh < 2; mh++)
#pragma unroll
    for (int mi = 0; mi < 4; mi++) {
      const int R = wmb + mh * 64 + mi * 16 + tr;
      const int r2 = R >> 1;
      offA[mh][mi] = r2 * 128 + ((((R & 1) << 2) | quad) ^ (r2 & 7)) * 16;
    }
#pragma unroll
  for (int ni = 0; ni < 4; ni++) {
    const int R = wnb + ni * 16 + tr;
    const int r2 = R >> 1;
    offB[ni] = r2 * 128 + ((((R & 1) << 2) | quad) ^ (r2 & 7)) * 16;
  }

  floatx4 acc[8][4];
#pragma unroll
  for (int mi = 0; mi < 8; mi++)
#pragma unroll
    for (int ni = 0; ni < 4; ni++) acc[mi][ni] = {0.f, 0.f, 0.f, 0.f};

#define STAGE_A(TT, KS) do { \
    char* d_ = smemc + ((2 * (TT) + (KS)) & 3) * UNIT + wdst; \
    async16(aSrc[0] + (TT) * 64 + (KS) * 32, d_); \
    async16(aSrc[1] + (TT) * 64 + (KS) * 32, d_ + 1024); \
  } while (0)
#define STAGE_B(TT, KS) do { \
    char* d_ = smemc + BOFF + ((2 * (TT) + (KS)) & 3) * UNIT + wdst; \
    async16(bSrc[0] + (TT) * 64 + (KS) * 32, d_); \
    async16(bSrc[1] + (TT) * 64 + (KS) * 32, d_ + 1024); \
  } while (0)

  // phase: 8 ds_read_b128 -> stage 1 unit -> barrier -> lgkmcnt(0) (+rule-18
  // sched_barrier) -> setprio(1) -> 16 MFMA -> setprio(0) -> [close] -> barrier
#define PHASE(SK, MH, STAGE_STMT, CLOSE_STMT) do { \
    const char* Ab_ = smemc + (SK) * UNIT; \
    const char* Bb_ = smemc + BOFF + (SK) * UNIT; \
    half8 af_[4], bf_[4]; \
    _Pragma("unroll") \
    for (int mi_ = 0; mi_ < 4; mi_++) af_[mi_] = *(const half8*)(Ab_ + offA[MH][mi_]); \
    _Pragma("unroll") \
    for (int ni_ = 0; ni_ < 4; ni_++) bf_[ni_] = *(const half8*)(Bb_ + offB[ni_]); \
    STAGE_STMT \
    __builtin_amdgcn_s_barrier(); \
    asm volatile("s_waitcnt lgkmcnt(0)" ::: "memory"); \
    __builtin_amdgcn_sched_barrier(0); \
    __builtin_amdgcn_s_setprio(1); \
    _Pragma("unroll") \
    for (int mi_ = 0; mi_ < 4; mi_++) \
      _Pragma("unroll") \
      for (int ni_ = 0; ni_ < 4; ni_++) \
        acc[(MH) * 4 + mi_][ni_] = __builtin_amdgcn_mfma_f32_16x16x32_f16( \
            af_[mi_], bf_[ni_], acc[(MH) * 4 + mi_][ni_], 0, 0, 0); \
    __builtin_amdgcn_s_setprio(0); \
    CLOSE_STMT \
    __builtin_amdgcn_s_barrier(); \
  } while (0)

  // ---- prologue: tile0 (4 units) + tile1 k0 (2 units); keep newest 2 in flight
  STAGE_A(0, 0); STAGE_B(0, 0);
  STAGE_A(0, 1); STAGE_B(0, 1);
  STAGE_A(1, 0); STAGE_B(1, 0);
  asm volatile("s_waitcnt vmcnt(4)" ::: "memory");
  __builtin_amdgcn_s_barrier();

  // ---- main loop: 4 phases per K-tile, counted vmcnt at tile boundary
#pragma unroll 2
  for (int t = 0; t < NKT; t++) {
    const int sk0 = (2 * t) & 3;
    const int sk1 = sk0 + 1;
    const bool f1 = (t + 1 < NKT);
    const bool f2 = (t + 2 < NKT);
    PHASE(sk0, 0, { if (f1) STAGE_A(t + 1, 1); }, {});
    PHASE(sk0, 1, { if (f1) STAGE_B(t + 1, 1); }, {});
    PHASE(sk1, 0, { if (f2) STAGE_A(t + 2, 0); }, {});
    PHASE(sk1, 1, { if (f2) STAGE_B(t + 2, 0); },
          { if (t == NKT - 2) { asm volatile("s_waitcnt vmcnt(0)" ::: "memory"); }
            else if (t < NKT - 2) { asm volatile("s_waitcnt vmcnt(4)" ::: "memory"); } });
  }
#undef PHASE
#undef STAGE_A
#undef STAGE_B

  // ---- epilogue: 8 passes of 32 rows x 256 cols through LDS, full-line stores
  constexpr int LST = 257;  // lbuf row stride (floats): pad breaks quad conflicts
  float* Yb = Y + (size_t)be * Kc * Jc;
#pragma unroll
  for (int pass = 0; pass < 8; pass++) {
    if ((wave >> 2) == (pass >> 2)) {
#pragma unroll
      for (int h = 0; h < 2; h++) {
        const int mi = (pass & 3) * 2 + h;
        const int rr = h * 16 + quad * 4;
#pragma unroll
        for (int ni = 0; ni < 4; ni++) {
          const int col = wnb + ni * 16 + tr;
#pragma unroll
          for (int r = 0; r < 4; r++)
            lbuf[(rr + r) * LST + col] = acc[mi][ni][r];
        }
      }
    }
    __syncthreads();
#pragma unroll
    for (int it = 0; it < 4; it++) {
      const int idx = tid + it * NT;
      const int rr = idx >> 6, c4 = idx & 63;
      floatx4 v = *(const floatx4*)&lbuf[rr * LST + c4 * 4];
      *(floatx4*)&Yb[(size_t)(k0 + pass * 32 + rr) * Jc + j0 + c4 * 4] = v;
    }
    __syncthreads();
  }
}

extern "C" void kernel_launch(void* const* d_in, const int* in_sizes, int n_in,
                              void* d_out, int out_size, void* d_ws, size_t ws_size,
                              hipStream_t stream) {
  const float* X = (const float*)d_in[0];
  const int* ind = (const int*)d_in[1];
  const float* W = (const float*)d_in[2];
  float* Y = (float*)d_out;

  const size_t nx = (size_t)Bc * Tc * Ic;
  _Float16* Xh = (_Float16*)d_ws;
  _Float16* WT = Xh + nx;

  cvt_kernel<<<Ec * 256 + 2048, 256, 0, stream>>>(X, Xh, (int)(nx / 8), W, WT);
  const int gemm_grid = (Bc * Ec) * (Kc / BM) * (Jc / BN);  // 512
  gemm_kernel<<<gemm_grid, NT, 0, stream>>>(ind, Xh, WT, Y);
}

// Round 2
// 309.937 us; speedup vs baseline: 1.0494x; 1.0144x over previous
//
#include <hip/hip_runtime.h>
#include <cstdint>
#include <cstddef>

// ExpertGather: Y[b,e,k,j] = sum_i X[b, ind[b,e,k], i] * W[e,i,j]
// B=4 T=4096 I=1024 E=16 K=512 J=1024
// Round 5: overlap LDS drain with MFMA.
//  - Removed per-phase explicit lgkmcnt(0)+sched_barrier: compiler emits
//    counted lgkm waits interleaved with the MFMA cluster (m97-verified
//    compiler behavior), so MFMA issue overlaps ds_read drain.
//  - Phase order (sk0,mh0),(sk0,mh1),(sk1,mh1),(sk1,mh0): bf fragments reused
//    in regs across same-sk phases -> 24 ds_read_b128/tile (was 32, floor).
//  - Barriers 8/tile -> 2/tile (mid-tile + boundary). Mid-tile barrier is
//    correctness-critical: STAGE(t+2,k0) overwrites the sk0 slot read in the
//    first half-tile; all waves' sk0 reads complete before their MFMAs, which
//    precede the mid barrier. Boundary keeps vmcnt(4) counted contract.
//  - Ring of 4 x 16KB units/operand, XOR swizzle, staging math, epilogue:
//    unchanged (verified rounds 3-4).

typedef float    floatx4 __attribute__((ext_vector_type(4)));
typedef _Float16 half8   __attribute__((ext_vector_type(8)));

constexpr int Bc = 4, Tc = 4096, Ic = 1024, Ec = 16, Kc = 512, Jc = 1024;
constexpr int BM = 256, BN = 256, BK = 64, NT = 512;
constexpr int NKT = Ic / BK;   // 16 K-tiles
constexpr int UNIT = 16384;    // one K-half unit: 256 rows x 32 halves x 2B
constexpr int BOFF = 4 * UNIT; // B-region byte offset in smem

__device__ __forceinline__ void async16(const void* g, void* l) {
  __builtin_amdgcn_global_load_lds(
      (const __attribute__((address_space(1))) uint32_t*)g,
      (__attribute__((address_space(3))) uint32_t*)l, 16, 0, 0);
}

// ---------- fused pre-pass: W transpose->fp16 (blocks 0..4095), X->fp16 (rest) ----------
__global__ void cvt_kernel(const float* __restrict__ X, _Float16* __restrict__ Xh, int n8,
                           const float* __restrict__ W, _Float16* __restrict__ WT) {
  __shared__ float tile[64][65];
  const int bidx = blockIdx.x;
  if (bidx >= Ec * 256) {
    int i = (bidx - Ec * 256) * blockDim.x + threadIdx.x;
    const int stride = 2048 * blockDim.x;
    for (; i < n8; i += stride) {
      floatx4 v0 = ((const floatx4*)X)[2 * i];
      floatx4 v1 = ((const floatx4*)X)[2 * i + 1];
      half8 h;
      h[0] = (_Float16)v0.x; h[1] = (_Float16)v0.y; h[2] = (_Float16)v0.z; h[3] = (_Float16)v0.w;
      h[4] = (_Float16)v1.x; h[5] = (_Float16)v1.y; h[6] = (_Float16)v1.z; h[7] = (_Float16)v1.w;
      ((half8*)Xh)[i] = h;
    }
    return;
  }
  const int bid = bidx;
  const int e  = bid >> 8;
  const int i0 = ((bid >> 4) & 15) * 64;
  const int j0 = (bid & 15) * 64;
  const int tid = threadIdx.x;
  const int r  = tid >> 4;
  const int c4 = tid & 15;
  const float* src = W + ((size_t)e << 20) + (size_t)i0 * Jc + j0;
#pragma unroll
  for (int s = 0; s < 4; s++) {
    int rr = r + s * 16;
    floatx4 v = *(const floatx4*)(src + (size_t)rr * Jc + c4 * 4);
    tile[rr][c4 * 4 + 0] = v.x; tile[rr][c4 * 4 + 1] = v.y;
    tile[rr][c4 * 4 + 2] = v.z; tile[rr][c4 * 4 + 3] = v.w;
  }
  __syncthreads();
  const int jj = tid >> 2;
  const int ig = tid & 3;
  half8 hv0, hv1;
#pragma unroll
  for (int q = 0; q < 8; q++) hv0[q] = (_Float16)tile[ig * 16 + q][jj];
#pragma unroll
  for (int q = 0; q < 8; q++) hv1[q] = (_Float16)tile[ig * 16 + 8 + q][jj];
  _Float16* dst = WT + ((size_t)e << 20) + (size_t)(j0 + jj) * Ic + i0 + ig * 16;
  ((half8*)dst)[0] = hv0;
  ((half8*)dst)[1] = hv1;
}

// ---------- main grouped GEMM ----------
// Grid 512 = 8 chunks x 8 sharers x 8 XCD-slots (unchanged, verified).
// MFMA layouts (m89-verified): A/B m(n)=lane&15, k=(lane>>4)*8+j;
// C/D col=lane&15, row=(lane>>4)*4+reg.
__global__ __launch_bounds__(NT, 2) void gemm_kernel(
    const int* __restrict__ ind32,
    const _Float16* __restrict__ Xh, const _Float16* __restrict__ WT,
    float* __restrict__ Y) {
  __shared__ alignas(16) unsigned char smem[8 * UNIT];  // 128 KB ring
  __shared__ int rowid[BM];
  __shared__ int is64_s;
  float* lbuf = (float*)smem;   // epilogue reuse (32x257 floats fits)
  char* smemc = (char*)smem;

  const int tid = threadIdx.x;
  const int bid = blockIdx.x;
  const int x = bid & 7, s = (bid >> 3) & 7, chunk = bid >> 6;
  const int g = chunk * 8 + x;       // 0..63 B-tile group
  const int e = g >> 2, nt = g & 3;  // expert, j-tile
  const int b = s >> 1, mt = s & 1;  // batch, k-tile
  const int be = b * Ec + e;
  const int k0 = mt * BM;
  const int j0 = nt * BN;

  // index dtype probe (int64 vs int32 storage), wave-parallel
  if (tid < 64) {
    int v = ind32[2 * tid + 1];
    unsigned long long m = __ballot(v != 0);
    if (tid == 0) is64_s = (m == 0ULL) ? 1 : 0;
  }
  __syncthreads();
  if (tid < BM) {
    int idx = be * Kc + k0 + tid;
    rowid[tid] = is64_s ? ind32[2 * idx] : ind32[idx];
  }
  __syncthreads();

  const int lane = tid & 63;
  const int wave = tid >> 6;           // 0..7
  const int wmb = (wave >> 2) * 128;   // wave m base (2 rows of waves)
  const int wnb = (wave & 3) * 64;     // wave n base (4 cols of waves)
  const int quad = lane >> 4;
  const int tr = lane & 15;

  // ---- staging source pointers (inverse-swizzled; dest is linear lane order) ----
  // slot s = wave*128 + q*64 + lane; r2=s>>3; p=s&7; pos=p^(r2&7);
  // row = 2*r2 + (pos>>2); chunk c = pos&3 (8 halves each).
  const _Float16* aSrc[2];
  const _Float16* bSrc[2];
#pragma unroll
  for (int q = 0; q < 2; q++) {
    const int sl = wave * 128 + q * 64 + lane;
    const int r2 = sl >> 3, p = sl & 7;
    const int pos = p ^ (r2 & 7);
    const int r = 2 * r2 + (pos >> 2);
    const int c = pos & 3;
    aSrc[q] = Xh + ((size_t)b * Tc + rowid[r]) * Ic + c * 8;
    bSrc[q] = WT + ((size_t)e * Jc + j0 + r) * Ic + c * 8;
  }
  const int wdst = wave * 2048;  // wave-uniform LDS dest base within a unit

  // ---- swizzled ds_read byte offsets within a unit ----
  int offA[2][4], offB[4];
#pragma unroll
  for (int mh = 0; mh < 2; mh++)
#pragma unroll
    for (int mi = 0; mi < 4; mi++) {
      const int R = wmb + mh * 64 + mi * 16 + tr;
      const int r2 = R >> 1;
      offA[mh][mi] = r2 * 128 + ((((R & 1) << 2) | quad) ^ (r2 & 7)) * 16;
    }
#pragma unroll
  for (int ni = 0; ni < 4; ni++) {
    const int R = wnb + ni * 16 + tr;
    const int r2 = R >> 1;
    offB[ni] = r2 * 128 + ((((R & 1) << 2) | quad) ^ (r2 & 7)) * 16;
  }

  floatx4 acc[8][4];
#pragma unroll
  for (int mi = 0; mi < 8; mi++)
#pragma unroll
    for (int ni = 0; ni < 4; ni++) acc[mi][ni] = {0.f, 0.f, 0.f, 0.f};

#define STAGE_A(TT, KS) do { \
    char* d_ = smemc + ((2 * (TT) + (KS)) & 3) * UNIT + wdst; \
    async16(aSrc[0] + (TT) * 64 + (KS) * 32, d_); \
    async16(aSrc[1] + (TT) * 64 + (KS) * 32, d_ + 1024); \
  } while (0)
#define STAGE_B(TT, KS) do { \
    char* d_ = smemc + BOFF + ((2 * (TT) + (KS)) & 3) * UNIT + wdst; \
    async16(bSrc[0] + (TT) * 64 + (KS) * 32, d_); \
    async16(bSrc[1] + (TT) * 64 + (KS) * 32, d_ + 1024); \
  } while (0)

#define LDAF(DST, SK, MH) do { \
    const char* Ab_ = smemc + (SK) * UNIT; \
    _Pragma("unroll") \
    for (int mi_ = 0; mi_ < 4; mi_++) DST[mi_] = *(const half8*)(Ab_ + offA[MH][mi_]); \
  } while (0)
#define LDBF(DST, SK) do { \
    const char* Bb_ = smemc + BOFF + (SK) * UNIT; \
    _Pragma("unroll") \
    for (int ni_ = 0; ni_ < 4; ni_++) DST[ni_] = *(const half8*)(Bb_ + offB[ni_]); \
  } while (0)
  // plain loads + data deps: compiler emits counted lgkmcnt(N) inside the
  // MFMA cluster, overlapping MFMA issue with ds_read drain.
#define MFMA16(MH, AF, BF) do { \
    __builtin_amdgcn_s_setprio(1); \
    _Pragma("unroll") \
    for (int mi_ = 0; mi_ < 4; mi_++) \
      _Pragma("unroll") \
      for (int ni_ = 0; ni_ < 4; ni_++) \
        acc[(MH) * 4 + mi_][ni_] = __builtin_amdgcn_mfma_f32_16x16x32_f16( \
            AF[mi_], BF[ni_], acc[(MH) * 4 + mi_][ni_], 0, 0, 0); \
    __builtin_amdgcn_s_setprio(0); \
  } while (0)

  // ---- prologue: stage (0,k0),(0,k1),(1,k0); keep newest 4 in flight
  STAGE_A(0, 0); STAGE_B(0, 0);
  STAGE_A(0, 1); STAGE_B(0, 1);
  STAGE_A(1, 0); STAGE_B(1, 0);
  asm volatile("s_waitcnt vmcnt(4)" ::: "memory");
  __builtin_amdgcn_s_barrier();

  // ---- main loop: branch-free body, 2 barriers/tile, counted vmcnt(4)
  for (int t = 0; t < NKT - 2; ++t) {
    const int sk0 = (2 * t) & 3, sk1 = sk0 + 1;
    half8 af0[4], af1[4], bf[4];
    // half-tile 1 (k-half 0): read sk0, stage (t+1,k1)
    LDAF(af0, sk0, 0);
    LDBF(bf, sk0);
    STAGE_A(t + 1, 1);
    LDAF(af1, sk0, 1);
    STAGE_B(t + 1, 1);
    MFMA16(0, af0, bf);
    MFMA16(1, af1, bf);
    __builtin_amdgcn_s_barrier();   // mid-tile: sk0 reads done CU-wide
    // half-tile 2 (k-half 1): read sk1, stage (t+2,k0) (overwrites sk0 slot)
    LDAF(af1, sk1, 1);
    LDBF(bf, sk1);
    STAGE_A(t + 2, 0);
    LDAF(af0, sk1, 0);
    STAGE_B(t + 2, 0);
    MFMA16(1, af1, bf);
    MFMA16(0, af0, bf);
    asm volatile("s_waitcnt vmcnt(4)" ::: "memory");
    __builtin_amdgcn_s_barrier();   // tile boundary: (t+1,k1) landed
  }
  // ---- t = NKT-2: stage (NKT-1,k1) only; drain vmcnt fully
  {
    const int t = NKT - 2;
    const int sk0 = (2 * t) & 3, sk1 = sk0 + 1;
    half8 af0[4], af1[4], bf[4];
    LDAF(af0, sk0, 0);
    LDBF(bf, sk0);
    STAGE_A(t + 1, 1);
    LDAF(af1, sk0, 1);
    STAGE_B(t + 1, 1);
    MFMA16(0, af0, bf);
    MFMA16(1, af1, bf);
    __builtin_amdgcn_s_barrier();
    LDAF(af1, sk1, 1);
    LDBF(bf, sk1);
    LDAF(af0, sk1, 0);
    MFMA16(1, af1, bf);
    MFMA16(0, af0, bf);
    asm volatile("s_waitcnt vmcnt(0)" ::: "memory");
    __builtin_amdgcn_s_barrier();
  }
  // ---- t = NKT-1: compute only
  {
    const int t = NKT - 1;
    const int sk0 = (2 * t) & 3, sk1 = sk0 + 1;
    half8 af0[4], af1[4], bf[4];
    LDAF(af0, sk0, 0);
    LDBF(bf, sk0);
    LDAF(af1, sk0, 1);
    MFMA16(0, af0, bf);
    MFMA16(1, af1, bf);
    LDAF(af1, sk1, 1);
    LDBF(bf, sk1);
    LDAF(af0, sk1, 0);
    MFMA16(1, af1, bf);
    MFMA16(0, af0, bf);
  }
  __syncthreads();  // all LDS reads done before lbuf epilogue reuse
#undef MFMA16
#undef LDBF
#undef LDAF
#undef STAGE_B
#undef STAGE_A

  // ---- epilogue: 8 passes of 32 rows x 256 cols through LDS, full-line stores
  constexpr int LST = 257;  // lbuf row stride (floats): pad breaks quad conflicts
  float* Yb = Y + (size_t)be * Kc * Jc;
#pragma unroll
  for (int pass = 0; pass < 8; pass++) {
    if ((wave >> 2) == (pass >> 2)) {
#pragma unroll
      for (int h = 0; h < 2; h++) {
        const int mi = (pass & 3) * 2 + h;
        const int rr = h * 16 + quad * 4;
#pragma unroll
        for (int ni = 0; ni < 4; ni++) {
          const int col = wnb + ni * 16 + tr;
#pragma unroll
          for (int r = 0; r < 4; r++)
            lbuf[(rr + r) * LST + col] = acc[mi][ni][r];
        }
      }
    }
    __syncthreads();
#pragma unroll
    for (int it = 0; it < 4; it++) {
      const int idx = tid + it * NT;
      const int rr = idx >> 6, c4 = idx & 63;
      floatx4 v = *(const floatx4*)&lbuf[rr * LST + c4 * 4];
      *(floatx4*)&Yb[(size_t)(k0 + pass * 32 + rr) * Jc + j0 + c4 * 4] = v;
    }
    __syncthreads();
  }
}

extern "C" void kernel_launch(void* const* d_in, const int* in_sizes, int n_in,
                              void* d_out, int out_size, void* d_ws, size_t ws_size,
                              hipStream_t stream) {
  const float* X = (const float*)d_in[0];
  const int* ind = (const int*)d_in[1];
  const float* W = (const float*)d_in[2];
  float* Y = (float*)d_out;

  const size_t nx = (size_t)Bc * Tc * Ic;
  _Float16* Xh = (_Float16*)d_ws;
  _Float16* WT = Xh + nx;

  cvt_kernel<<<Ec * 256 + 2048, 256, 0, stream>>>(X, Xh, (int)(nx / 8), W, WT);
  const int gemm_grid = (Bc * Ec) * (Kc / BM) * (Jc / BN);  // 512
  gemm_kernel<<<gemm_grid, NT, 0, stream>>>(ind, Xh, WT, Y);
}